// Round 16
// baseline (343.241 us; speedup 1.0000x reference)
//
#include <hip/hip_runtime.h>
#include <math.h>

#define L 8
#define N 32768
#define H 404
#define D 128
#define F 532
#define KT 9              // K-tiles of 64 (64*9=576; cols >=532 are zero in B)
#define CHAINB 101        // chain blocks (one wave per hidden j)

typedef __attribute__((ext_vector_type(8))) _Float16 half8;
typedef __attribute__((ext_vector_type(4))) float f32x4;
typedef __attribute__((address_space(3))) unsigned int as3_u32;
typedef __attribute__((address_space(1))) unsigned int as1_u32;

// workspace layout (float offsets)
#define WS_WH2     0                        // 9*128*64 fp16 = 36864 floats
#define WS_HMAXK   (WS_WH2 + 36864)         // 8*128 uint keys
#define WS_HSEL    (WS_HMAXK + L * D)       // 7*128
#define WS_HBUF    (WS_HSEL + (L - 1) * D)  // 2*404
#define WS_HS      (WS_HBUF + 2 * H)        // 128
#define WS_SCAL    (WS_HS + D)              // [1]=M, [2]=S
#define WS_CNT     (WS_SCAL + 4)            // [0] spare, [1]=cntG, [3..9]=hopcnt[7]
#define WS_PM      (WS_CNT + 16)            // 256 block partial max
#define WS_PS      (WS_PM + 256)            // 256 block partial sum
#define WS_LOGITS  (WS_PS + 256)            // 32769

__device__ __forceinline__ unsigned encf(float f) {
    unsigned u = __float_as_uint(f);
    return (u & 0x80000000u) ? ~u : (u | 0x80000000u);
}
__device__ __forceinline__ float decf(unsigned u) {
    unsigned b = (u & 0x80000000u) ? (u ^ 0x80000000u) : ~u;
    return __uint_as_float(b);
}
__device__ __forceinline__ float sigmoidf_(float x) {
    return 1.0f / (1.0f + __expf(-x));
}
__device__ __forceinline__ unsigned pk_f16(float a, float b) {
    auto h = __builtin_amdgcn_cvt_pkrtz(a, b);
    return *(unsigned*)&h;
}
__device__ __forceinline__ half8 pack8(float4 x0, float4 x1) {
    uint4 u = { pk_f16(x0.x, x0.y), pk_f16(x0.z, x0.w),
                pk_f16(x1.x, x1.y), pk_f16(x1.z, x1.w) };
    return *(half8*)&u;
}
__device__ __forceinline__ void gld16(const void* g, void* l) {
    __builtin_amdgcn_global_load_lds((const as1_u32*)g, (as3_u32*)l, 16, 0, 0);
}
__device__ __forceinline__ float aload(const float* p) {
    return __hip_atomic_load(p, __ATOMIC_RELAXED, __HIP_MEMORY_SCOPE_AGENT);
}
__device__ __forceinline__ unsigned aloadu(const unsigned* p) {
    return __hip_atomic_load(p, __ATOMIC_RELAXED, __HIP_MEMORY_SCOPE_AGENT);
}
__device__ __forceinline__ void astore(float* p, float v) {
    __hip_atomic_store(p, v, __ATOMIC_RELAXED, __HIP_MEMORY_SCOPE_AGENT);
}

// ---- prep: pre-swizzled fp16 B tiles; init keys + counters ----
__global__ void k_prep(const float* __restrict__ Wfa, unsigned short* __restrict__ wh2,
                       unsigned* __restrict__ keys, unsigned* __restrict__ cnts) {
    int i = blockIdx.x * 256 + threadIdx.x;
    if (i < L * D) keys[i] = 0u;           // decodes below all finite values
    if (i >= 2000 && i < 2016) cnts[i - 2000] = 0u;
    if (i >= KT * 128 * 8) return;
    int kt = i / (128 * 8);
    int rem = i - kt * 128 * 8;
    int c = rem >> 3, j = rem & 7;
    int k0 = kt * 64 + (j ^ (c & 7)) * 8;
    unsigned short v[8];
#pragma unroll
    for (int e = 0; e < 8; ++e) {
        int k = k0 + e;
        float x = (k < F) ? Wfa[c * F + k] : 0.0f;
        _Float16 h = (_Float16)x;
        v[e] = *(unsigned short*)&h;
    }
    *(uint4*)(wh2 + (long)i * 8) = *(uint4*)v;
}

// ---- MAIN: chain (blocks 0..100, fused gi+GRU+hSt, hop-pipelined) +
//            einsum hops 0..6 (blocks 101.., r9 body, signals hopcnt) ----
__global__ __launch_bounds__(256, 3)
void k_main(const float* __restrict__ nb, const unsigned short* __restrict__ wh2,
            const float* __restrict__ bfa, const int* __restrict__ aid,
            const float* __restrict__ pn, const float* __restrict__ query,
            const float* __restrict__ Wih, const float* __restrict__ bih,
            const float* __restrict__ Whh, const float* __restrict__ bhh,
            const float* __restrict__ Wfs, const float* __restrict__ bfs,
            unsigned* __restrict__ hmaxk, float* __restrict__ hsel,
            float* __restrict__ hbuf, float* __restrict__ hs_ws,
            unsigned* __restrict__ cnts) {
    __shared__ float As[128 * 64];          // 32 KB (einsum A / chain xs)
    __shared__ unsigned short Bs[128 * 64]; // 16 KB

    const int bid = blockIdx.x;
    const int tid = threadIdx.x;
    const int lane = tid & 63, w = tid >> 6;
    unsigned* cntG = cnts + 1;
    unsigned* hopcnt = cnts + 3;

    if (bid < CHAINB) {
        // ================== chain: fused gi + GRU, pipelined ==================
        float* xs = As;                       // 384 floats
        const int j = bid * 4 + w;            // hidden index 0..403
        // cache W_ih gate rows (r,z,n) and W_hh rows for j
        float wir[6], wiz[6], win[6];
#pragma unroll
        for (int c = 0; c < 6; ++c) {
            int k = lane + c * 64;
            wir[c] = Wih[(long)j * 384 + k];
            wiz[c] = Wih[(long)(H + j) * 384 + k];
            win[c] = Wih[(long)(2 * H + j) * 384 + k];
        }
        float whr[7], whz[7], whn[7];
#pragma unroll
        for (int c = 0; c < 7; ++c) {
            int i = lane + c * 64;
            bool ok = i < H;
            whr[c] = ok ? Whh[(long)j * H + i]           : 0.f;
            whz[c] = ok ? Whh[(long)(H + j) * H + i]     : 0.f;
            whn[c] = ok ? Whh[(long)(2 * H + j) * H + i] : 0.f;
        }
        const float b_ir = bih[j], b_iz = bih[H + j], b_in = bih[2 * H + j];
        const float b_hr = bhh[j], b_hz = bhh[H + j], b_hn = bhh[2 * H + j];

        for (int t = 0; t < L; ++t) {
            if (t > 0) {   // wait for einsum hop t-1 (256 blocks)
                __syncthreads();
                if (tid == 0) {
                    while (__hip_atomic_load(hopcnt + (t - 1), __ATOMIC_ACQUIRE,
                                             __HIP_MEMORY_SCOPE_AGENT) < 256u)
                        __builtin_amdgcn_s_sleep(8);
                }
                __syncthreads();
            }
            // stage x_t = [hmax[t-1], hsel[t-1], pn[t]] (t=0: [0,0,pn[0]])
            for (int i = tid; i < 384; i += 256) {
                float x;
                if (t == 0)       x = (i < 256) ? 0.f : pn[i - 256];
                else if (i < 128) x = decf(aloadu(hmaxk + (t - 1) * D + i));
                else if (i < 256) x = aload(hsel + (t - 1) * D + (i - 128));
                else              x = pn[t * D + (i - 256)];
                xs[i] = x;
            }
            __syncthreads();
            // gi dots (3 x 384) + Whh dots (3 x 404)
            float gir = 0.f, giz = 0.f, gin = 0.f;
#pragma unroll
            for (int c = 0; c < 6; ++c) {
                float xv = xs[lane + c * 64];
                gir = fmaf(wir[c], xv, gir);
                giz = fmaf(wiz[c], xv, giz);
                gin = fmaf(win[c], xv, gin);
            }
            const float* hin = (t == 0) ? query : (hbuf + ((t - 1) & 1) * H);
            float pr = 0.f, pz = 0.f, pn2 = 0.f;
#pragma unroll
            for (int c = 0; c < 7; ++c) {
                int i = lane + c * 64;
                float hv = 0.f;
                if (i < H) hv = (t == 0) ? hin[i] : aload(hin + i);
                pr  = fmaf(whr[c], hv, pr);
                pz  = fmaf(whz[c], hv, pz);
                pn2 = fmaf(whn[c], hv, pn2);
            }
            for (int off = 1; off < 64; off <<= 1) {
                gir += __shfl_xor(gir, off, 64);
                giz += __shfl_xor(giz, off, 64);
                gin += __shfl_xor(gin, off, 64);
                pr  += __shfl_xor(pr, off, 64);
                pz  += __shfl_xor(pz, off, 64);
                pn2 += __shfl_xor(pn2, off, 64);
            }
            if (lane == 0) {
                float* hout = hbuf + (t & 1) * H;
                float hprev = (t == 0) ? hin[j] : aload(hin + j);
                float r  = sigmoidf_((gir + b_ir) + pr + b_hr);
                float z  = sigmoidf_((giz + b_iz) + pz + b_hz);
                float nn = tanhf((gin + b_in) + r * (pn2 + b_hn));
                astore(hout + j, (1.0f - z) * nn + z * hprev);
            }
            // barrier among 101 chain blocks (h_t published)
            __syncthreads();
            if (tid == 0) {
                __hip_atomic_fetch_add(cntG, 1u, __ATOMIC_RELEASE,
                                       __HIP_MEMORY_SCOPE_AGENT);
                unsigned target = (unsigned)CHAINB * (t + 1);
                while (__hip_atomic_load(cntG, __ATOMIC_ACQUIRE,
                                         __HIP_MEMORY_SCOPE_AGENT) < target)
                    __builtin_amdgcn_s_sleep(2);
            }
            __syncthreads();
        }
        // ---- hSt = W_fs qt + b_fs : blocks 0..31 ----
        if (bid < 32) {
            const float* qt = hbuf + H;    // hbuf[1] ((L-1)&1 == 1)
            int d = bid * 4 + w;
            float s = 0.f;
#pragma unroll
            for (int c = 0; c < 7; ++c) {
                int i = lane + c * 64;
                if (i < H) s = fmaf(aload(qt + i), Wfs[(long)d * H + i], s);
            }
            for (int off = 1; off < 64; off <<= 1) s += __shfl_xor(s, off, 64);
            if (lane == 0) astore(&hs_ws[d], s + bfs[d]);
        }
        return;
    }

    // ================== einsum hops 0..6 (r9 body) ==================
    const int idx = bid - CHAINB;
    const int l_hop = idx >> 8;
    const int row0 = (idx & 255) * 128;
    const int wm = w >> 1, wn = w & 1;
    const int lr = lane & 15, kg = lane >> 4;

    const float* xbase = nb + ((long)l_hop * N + row0) * F;

    f32x4 acc[4][4];
    float bv[4];
#pragma unroll
    for (int n = 0; n < 4; ++n) bv[n] = bfa[wn * 64 + n * 16 + lr];
#pragma unroll
    for (int m = 0; m < 4; ++m)
#pragma unroll
        for (int n = 0; n < 4; ++n) {
            acc[m][n][0] = bv[n]; acc[m][n][1] = bv[n];
            acc[m][n][2] = bv[n]; acc[m][n][3] = bv[n];
        }

    const int srow = lane >> 4;
    const int scp  = lane & 15;

    for (int kt = 0; kt < KT; ++kt) {
        const int fc = kt * 64;
        __syncthreads();
#pragma unroll
        for (int it = 0; it < 8; ++it) {
            int rbase = it * 16 + w * 4;
            int row = rbase + srow;
            int cg = scp ^ (row & 7);
            int col0 = fc + cg * 4;
            const float* src = xbase + (long)row * F + ((col0 < F) ? col0 : 0);
            gld16(src, (char*)As + rbase * 256);
        }
#pragma unroll
        for (int it = 0; it < 4; ++it) {
            int rb = it * 32 + w * 8;
            const char* src = (const char*)wh2 + (long)kt * 16384 + rb * 128 + lane * 16;
            gld16(src, (char*)Bs + rb * 128);
        }
        __syncthreads();

#pragma unroll
        for (int ks = 0; ks < 2; ++ks) {
            half8 b[4];
#pragma unroll
            for (int n = 0; n < 4; ++n) {
                int col = wn * 64 + n * 16 + lr;
                int ch = (ks * 4 + kg) ^ (col & 7);
                b[n] = *(const half8*)((const char*)Bs + col * 128 + ch * 16);
            }
#pragma unroll
            for (int m = 0; m < 4; ++m) {
                int row = wm * 64 + m * 16 + lr;
                int c0 = ks * 8 + kg * 2;
                const char* base = (const char*)As + row * 256;
                float4 x0 = *(const float4*)(base + (((c0)     ^ (row & 7)) << 4));
                float4 x1 = *(const float4*)(base + (((c0 + 1) ^ (row & 7)) << 4));
                half8 a = pack8(x0, x1);
#pragma unroll
                for (int n = 0; n < 4; ++n)
                    acc[m][n] = __builtin_amdgcn_mfma_f32_16x16x32_f16(a, b[n], acc[m][n], 0, 0, 0);
            }
        }
    }

    __syncthreads();

    {   // selected-action row (device-visible store)
        int br = aid[l_hop] - row0;
        if (br >= 0 && br < 128 && (br >> 6) == wm && ((br >> 2) & 3) == kg) {
            int msel = (br >> 4) & 3, rsel = br & 3;
#pragma unroll
            for (int n = 0; n < 4; ++n) {
                float vsel = 0.f;
#pragma unroll
                for (int m = 0; m < 4; ++m)
#pragma unroll
                    for (int r = 0; r < 4; ++r)
                        if (m == msel && r == rsel) vsel = acc[m][n][r];
                astore(&hsel[l_hop * D + wn * 64 + n * 16 + lr], vsel);
            }
        }
    }

    float cmax[4];
#pragma unroll
    for (int n = 0; n < 4; ++n) {
        float m0 = acc[0][n][0];
#pragma unroll
        for (int m = 0; m < 4; ++m)
#pragma unroll
            for (int r = 0; r < 4; ++r) m0 = fmaxf(m0, acc[m][n][r]);
        m0 = fmaxf(m0, __shfl_xor(m0, 16, 64));
        m0 = fmaxf(m0, __shfl_xor(m0, 32, 64));
        cmax[n] = m0;
    }
    float* wmaxp = (float*)As;
    if (kg == 0) {
#pragma unroll
        for (int n = 0; n < 4; ++n)
            wmaxp[wm * 128 + wn * 64 + n * 16 + lr] = cmax[n];
    }
    __syncthreads();
    if (tid < 128) {
        float mval = fmaxf(wmaxp[tid], wmaxp[128 + tid]);
        atomicMax(&hmaxk[l_hop * D + tid], encf(mval));
    }
    // signal hop completion (after all block writes)
    __syncthreads();
    if (tid == 0)
        __hip_atomic_fetch_add(hopcnt + l_hop, 1u, __ATOMIC_RELEASE,
                               __HIP_MEMORY_SCOPE_AGENT);
}

// ---- hop 7: einsum + hmax7 + in-register uks + block softmax partials ----
__global__ __launch_bounds__(256, 3)
void k_big7(const float* __restrict__ nb, const unsigned short* __restrict__ wh2,
            const float* __restrict__ bfa, unsigned* __restrict__ hmaxk,
            const float* __restrict__ hs_ws, float* __restrict__ logits,
            float* __restrict__ pm, float* __restrict__ ps) {
    __shared__ float As[128 * 64];
    __shared__ unsigned short Bs[128 * 64];
    __shared__ float sm2[2], ss2[2];

    const int bid = blockIdx.x;
    const int row0 = bid * 128;
    const int tid = threadIdx.x;
    const int lane = tid & 63, w = tid >> 6;
    const int wm = w >> 1, wn = w & 1;
    const int lr = lane & 15, kg = lane >> 4;

    const float* xbase = nb + ((long)7 * N + row0) * F;

    f32x4 acc[4][4];
    float bv[4];
#pragma unroll
    for (int n = 0; n < 4; ++n) bv[n] = bfa[wn * 64 + n * 16 + lr];
#pragma unroll
    for (int m = 0; m < 4; ++m)
#pragma unroll
        for (int n = 0; n < 4; ++n) {
            acc[m][n][0] = bv[n]; acc[m][n][1] = bv[n];
            acc[m][n][2] = bv[n]; acc[m][n][3] = bv[n];
        }

    const int srow = lane >> 4;
    const int scp  = lane & 15;

    for (int kt = 0; kt < KT; ++kt) {
        const int fc = kt * 64;
        __syncthreads();
#pragma unroll
        for (int it = 0; it < 8; ++it) {
            int rbase = it * 16 + w * 4;
            int row = rbase + srow;
            int cg = scp ^ (row & 7);
            int col0 = fc + cg * 4;
            const float* src = xbase + (long)row * F + ((col0 < F) ? col0 : 0);
            gld16(src, (char*)As + rbase * 256);
        }
#pragma unroll
        for (int it = 0; it < 4; ++it) {
            int rb = it * 32 + w * 8;
            const char* src = (const char*)wh2 + (long)kt * 16384 + rb * 128 + lane * 16;
            gld16(src, (char*)Bs + rb * 128);
        }
        __syncthreads();

#pragma unroll
        for (int ks = 0; ks < 2; ++ks) {
            half8 b[4];
#pragma unroll
            for (int n = 0; n < 4; ++n) {
                int col = wn * 64 + n * 16 + lr;
                int ch = (ks * 4 + kg) ^ (col & 7);
                b[n] = *(const half8*)((const char*)Bs + col * 128 + ch * 16);
            }
#pragma unroll
            for (int m = 0; m < 4; ++m) {
                int row = wm * 64 + m * 16 + lr;
                int c0 = ks * 8 + kg * 2;
                const char* base = (const char*)As + row * 256;
                float4 x0 = *(const float4*)(base + (((c0)     ^ (row & 7)) << 4));
                float4 x1 = *(const float4*)(base + (((c0 + 1) ^ (row & 7)) << 4));
                half8 a = pack8(x0, x1);
#pragma unroll
                for (int n = 0; n < 4; ++n)
                    acc[m][n] = __builtin_amdgcn_mfma_f32_16x16x32_f16(a, b[n], acc[m][n], 0, 0, 0);
            }
        }
    }

    __syncthreads();

    // uks[row] = sum_col hs[col] * acc (bias folded in acc init)
    float hsv[4];
#pragma unroll
    for (int n = 0; n < 4; ++n) hsv[n] = hs_ws[wn * 64 + n * 16 + lr];
    float p[4][4];
#pragma unroll
    for (int m = 0; m < 4; ++m)
#pragma unroll
        for (int r = 0; r < 4; ++r) {
            float s = hsv[0] * acc[m][0][r];
            s = fmaf(hsv[1], acc[m][1][r], s);
            s = fmaf(hsv[2], acc[m][2][r], s);
            s = fmaf(hsv[3], acc[m][3][r], s);
#pragma unroll
            for (int off = 1; off < 16; off <<= 1)
                s += __shfl_xor(s, off, 64);
            p[m][r] = s;
        }
    float* part = (float*)As;
    if (lr == 0) {
#pragma unroll
        for (int m = 0; m < 4; ++m)
#pragma unroll
            for (int r = 0; r < 4; ++r)
                part[wn * 128 + wm * 64 + m * 16 + kg * 4 + r] = p[m][r];
    }
    __syncthreads();
    float val = -3.4e38f, sv = 0.f;
    if (tid < 128) {
        val = part[tid] + part[128 + tid];
        logits[1 + row0 + tid] = val;
        sv = 1.0f;
    }
    float mv = val;
    for (int off = 1; off < 64; off <<= 1) {
        float m2 = __shfl_xor(mv, off, 64);
        float s2 = __shfl_xor(sv, off, 64);
        float M = fmaxf(mv, m2);
        sv = sv * __expf(mv - M) + s2 * __expf(m2 - M);
        mv = M;
    }
    if (lane == 0 && w < 2) { sm2[w] = mv; ss2[w] = sv; }
    __syncthreads();
    if (tid == 0) {
        float M = fmaxf(sm2[0], sm2[1]);
        float S = ss2[0] * __expf(sm2[0] - M) + ss2[1] * __expf(sm2[1] - M);
        pm[bid] = M; ps[bid] = S;
    }
    __syncthreads();

    float cmax[4];
#pragma unroll
    for (int n = 0; n < 4; ++n) {
        float m0 = acc[0][n][0];
#pragma unroll
        for (int m = 0; m < 4; ++m)
#pragma unroll
            for (int r = 0; r < 4; ++r) m0 = fmaxf(m0, acc[m][n][r]);
        m0 = fmaxf(m0, __shfl_xor(m0, 16, 64));
        m0 = fmaxf(m0, __shfl_xor(m0, 32, 64));
        cmax[n] = m0;
    }
    float* wmaxp = (float*)As;
    if (kg == 0) {
#pragma unroll
        for (int n = 0; n < 4; ++n)
            wmaxp[wm * 128 + wn * 64 + n * 16 + lr] = cmax[n];
    }
    __syncthreads();
    if (tid < 128) {
        float mval = fmaxf(wmaxp[tid], wmaxp[128 + tid]);
        atomicMax(&hmaxk[7 * D + tid], encf(mval));
    }
}

// ---- u0 + reduce 256 block partials -> M, S ----
__global__ void k_sm12(const float* __restrict__ hs_ws, const float* __restrict__ Wfp,
                       const float* __restrict__ bfp, const unsigned* __restrict__ hmaxk,
                       const float* __restrict__ pm, const float* __restrict__ ps,
                       float* __restrict__ logits, float* __restrict__ scal) {
    __shared__ float red[4], reds[4], u0sh;
    int tid = threadIdx.x, lane = tid & 63, wid = tid >> 6;
    if (tid < 64) {
        float s = hs_ws[tid] * Wfp[tid];
        s = fmaf(hs_ws[tid + 64], Wfp[tid + 64], s);
        s = fmaf(decf(hmaxk[(L - 1) * D + tid]),      Wfp[D + tid],      s);
        s = fmaf(decf(hmaxk[(L - 1) * D + tid + 64]), Wfp[D + tid + 64], s);
        for (int off = 1; off < 64; off <<= 1) s += __shfl_xor(s, off, 64);
        if (tid == 0) { u0sh = s + bfp[0]; logits[0] = u0sh; }
    }
    __syncthreads();
    float m = -3.4e38f, s = 0.f;
    if (tid < 256) { m = pm[tid]; s = ps[tid]; }
    for (int off = 1; off < 64; off <<= 1) {
        float m2 = __shfl_xor(m, off, 64);
        float s2 = __shfl_xor(s, off, 64);
        float M = fmaxf(m, m2);
        s = s * __expf(m - M) + s2 * __expf(m2 - M);
        m = M;
    }
    if (lane == 0 && wid < 4) { red[wid] = m; reds[wid] = s; }
    __syncthreads();
    if (tid == 0) {
        float M = u0sh, S = 1.0f;
        for (int k = 0; k < 4; ++k) {
            float Mn = fmaxf(M, red[k]);
            S = S * __expf(M - Mn) + reds[k] * __expf(red[k] - Mn);
            M = Mn;
        }
        scal[1] = M; scal[2] = S;
    }
}

__global__ void k_sm3(const float* __restrict__ logits, const float* __restrict__ scal,
                      float* __restrict__ out) {
    int i = blockIdx.x * 256 + threadIdx.x;
    if (i <= N) out[i] = __expf(logits[i] - scal[1]) / scal[2];
}

extern "C" void kernel_launch(void* const* d_in, const int* in_sizes, int n_in,
                              void* d_out, int out_size, void* d_ws, size_t ws_size,
                              hipStream_t stream) {
    const float* query = (const float*)d_in[0];
    const float* pn    = (const float*)d_in[1];
    const float* nb    = (const float*)d_in[2];
    const int*   aid   = (const int*)d_in[3];
    const float* Wih   = (const float*)d_in[4];
    const float* Whh   = (const float*)d_in[5];
    const float* bih   = (const float*)d_in[6];
    const float* bhh   = (const float*)d_in[7];
    const float* Wfa   = (const float*)d_in[8];
    const float* bfa   = (const float*)d_in[9];
    const float* Wfs   = (const float*)d_in[10];
    const float* bfs   = (const float*)d_in[11];
    const float* Wfp   = (const float*)d_in[12];
    const float* bfp   = (const float*)d_in[13];

    float* ws = (float*)d_ws;
    unsigned short* wh2   = (unsigned short*)(ws + WS_WH2);
    unsigned*       hmaxk = (unsigned*)(ws + WS_HMAXK);
    unsigned*       cnts  = (unsigned*)(ws + WS_CNT);
    float* hsel   = ws + WS_HSEL;
    float* hbuf   = ws + WS_HBUF;
    float* hs_ws  = ws + WS_HS;
    float* scal   = ws + WS_SCAL;
    float* pm     = ws + WS_PM;
    float* psum   = ws + WS_PS;
    float* logits = ws + WS_LOGITS;
    float* out    = (float*)d_out;

    k_prep<<<(KT * 128 * 8 + 255) / 256, 256, 0, stream>>>(Wfa, wh2, hmaxk, cnts);
    k_main<<<CHAINB + 7 * 256, 256, 0, stream>>>(nb, wh2, bfa, aid, pn, query,
                                                 Wih, bih, Whh, bhh, Wfs, bfs,
                                                 hmaxk, hsel, hbuf, hs_ws, cnts);
    k_big7<<<256, 256, 0, stream>>>(nb, wh2, bfa, hmaxk, hs_ws, logits, pm, psum);
    k_sm12<<<1, 1024, 0, stream>>>(hs_ws, Wfp, bfp, hmaxk, pm, psum, logits, scal);
    k_sm3 <<<(N + 1 + 255) / 256, 256, 0, stream>>>(logits, scal, out);
}

// Round 17
// 197.866 us; speedup vs baseline: 1.7347x; 1.7347x over previous
//
#include <hip/hip_runtime.h>
#include <math.h>

#define L 8
#define N 32768
#define H 404
#define D 128
#define F 532
#define KT 9              // K-tiles of 64 (64*9=576; cols >=532 are zero in B)
#define GRU_BLOCKS 101    // one wave per hidden index

typedef __attribute__((ext_vector_type(8))) _Float16 half8;
typedef __attribute__((ext_vector_type(4))) float f32x4;
typedef __attribute__((address_space(3))) unsigned int as3_u32;
typedef __attribute__((address_space(1))) unsigned int as1_u32;

// workspace layout (float offsets)
#define WS_WH2     0                        // 9*128*64 fp16 = 36864 floats
#define WS_HMAXK   (WS_WH2 + 36864)         // 8*128 uint keys
#define WS_HSEL    (WS_HMAXK + L * D)       // 7*128
#define WS_HBUF    (WS_HSEL + (L - 1) * D)  // 2*404
#define WS_HS      (WS_HBUF + 2 * H)        // 128
#define WS_CNT     (WS_HS + D)              // [1]=cntG, [2]=cntB, ... 16 slots
#define WS_PM      (WS_CNT + 16)            // 256 block partial max
#define WS_PS      (WS_PM + 256)            // 256 block partial sum

__device__ __forceinline__ unsigned encf(float f) {
    unsigned u = __float_as_uint(f);
    return (u & 0x80000000u) ? ~u : (u | 0x80000000u);
}
__device__ __forceinline__ float decf(unsigned u) {
    unsigned b = (u & 0x80000000u) ? (u ^ 0x80000000u) : ~u;
    return __uint_as_float(b);
}
__device__ __forceinline__ float sigmoidf_(float x) {
    return 1.0f / (1.0f + __expf(-x));
}
__device__ __forceinline__ unsigned pk_f16(float a, float b) {
    auto h = __builtin_amdgcn_cvt_pkrtz(a, b);
    return *(unsigned*)&h;
}
__device__ __forceinline__ half8 pack8(float4 x0, float4 x1) {
    uint4 u = { pk_f16(x0.x, x0.y), pk_f16(x0.z, x0.w),
                pk_f16(x1.x, x1.y), pk_f16(x1.z, x1.w) };
    return *(half8*)&u;
}
__device__ __forceinline__ void gld16(const void* g, void* l) {
    __builtin_amdgcn_global_load_lds((const as1_u32*)g, (as3_u32*)l, 16, 0, 0);
}
__device__ __forceinline__ float aload(const float* p) {
    return __hip_atomic_load(p, __ATOMIC_RELAXED, __HIP_MEMORY_SCOPE_AGENT);
}
__device__ __forceinline__ unsigned aloadu(const unsigned* p) {
    return __hip_atomic_load(p, __ATOMIC_RELAXED, __HIP_MEMORY_SCOPE_AGENT);
}
__device__ __forceinline__ void astore(float* p, float v) {
    __hip_atomic_store(p, v, __ATOMIC_RELAXED, __HIP_MEMORY_SCOPE_AGENT);
}

// ---- prep: pre-swizzled fp16 B tiles; init keys + counters ----
__global__ void k_prep(const float* __restrict__ Wfa, unsigned short* __restrict__ wh2,
                       unsigned* __restrict__ keys, unsigned* __restrict__ cnts) {
    int i = blockIdx.x * 256 + threadIdx.x;
    if (i < L * D) keys[i] = 0u;           // decodes below all finite values
    if (i >= 2000 && i < 2016) cnts[i - 2000] = 0u;
    if (i >= KT * 128 * 8) return;
    int kt = i / (128 * 8);
    int rem = i - kt * 128 * 8;
    int c = rem >> 3, j = rem & 7;
    int k0 = kt * 64 + (j ^ (c & 7)) * 8;
    unsigned short v[8];
#pragma unroll
    for (int e = 0; e < 8; ++e) {
        int k = k0 + e;
        float x = (k < F) ? Wfa[c * F + k] : 0.0f;
        _Float16 h = (_Float16)x;
        v[e] = *(unsigned short*)&h;
    }
    *(uint4*)(wh2 + (long)i * 8) = *(uint4*)v;
}

// ---- big einsum hops 0..6 (r9 body, proven) ----
__global__ __launch_bounds__(256, 3)
void k_big0(const float* __restrict__ nb, const unsigned short* __restrict__ wh2,
            const float* __restrict__ bfa, const int* __restrict__ aid,
            unsigned* __restrict__ hmaxk, float* __restrict__ hsel) {
    __shared__ float As[128 * 64];          // 32 KB
    __shared__ unsigned short Bs[128 * 64]; // 16 KB

    const int bid = blockIdx.x;
    const int l_hop = bid >> 8;
    const int row0 = (bid & 255) * 128;
    const int tid = threadIdx.x;
    const int lane = tid & 63, w = tid >> 6;
    const int wm = w >> 1, wn = w & 1;
    const int lr = lane & 15, kg = lane >> 4;

    const float* xbase = nb + ((long)l_hop * N + row0) * F;

    f32x4 acc[4][4];
    float bv[4];
#pragma unroll
    for (int n = 0; n < 4; ++n) bv[n] = bfa[wn * 64 + n * 16 + lr];
#pragma unroll
    for (int m = 0; m < 4; ++m)
#pragma unroll
        for (int n = 0; n < 4; ++n) {
            acc[m][n][0] = bv[n]; acc[m][n][1] = bv[n];
            acc[m][n][2] = bv[n]; acc[m][n][3] = bv[n];
        }

    const int srow = lane >> 4;
    const int scp  = lane & 15;

    for (int kt = 0; kt < KT; ++kt) {
        const int fc = kt * 64;
        __syncthreads();
#pragma unroll
        for (int it = 0; it < 8; ++it) {
            int rbase = it * 16 + w * 4;
            int row = rbase + srow;
            int cg = scp ^ (row & 7);
            int col0 = fc + cg * 4;
            const float* src = xbase + (long)row * F + ((col0 < F) ? col0 : 0);
            gld16(src, (char*)As + rbase * 256);
        }
#pragma unroll
        for (int it = 0; it < 4; ++it) {
            int rb = it * 32 + w * 8;
            const char* src = (const char*)wh2 + (long)kt * 16384 + rb * 128 + lane * 16;
            gld16(src, (char*)Bs + rb * 128);
        }
        __syncthreads();

#pragma unroll
        for (int ks = 0; ks < 2; ++ks) {
            half8 b[4];
#pragma unroll
            for (int n = 0; n < 4; ++n) {
                int col = wn * 64 + n * 16 + lr;
                int ch = (ks * 4 + kg) ^ (col & 7);
                b[n] = *(const half8*)((const char*)Bs + col * 128 + ch * 16);
            }
#pragma unroll
            for (int m = 0; m < 4; ++m) {
                int row = wm * 64 + m * 16 + lr;
                int c0 = ks * 8 + kg * 2;
                const char* base = (const char*)As + row * 256;
                float4 x0 = *(const float4*)(base + (((c0)     ^ (row & 7)) << 4));
                float4 x1 = *(const float4*)(base + (((c0 + 1) ^ (row & 7)) << 4));
                half8 a = pack8(x0, x1);
#pragma unroll
                for (int n = 0; n < 4; ++n)
                    acc[m][n] = __builtin_amdgcn_mfma_f32_16x16x32_f16(a, b[n], acc[m][n], 0, 0, 0);
            }
        }
    }

    __syncthreads();

    {   // selected-action row
        int br = aid[l_hop] - row0;
        if (br >= 0 && br < 128 && (br >> 6) == wm && ((br >> 2) & 3) == kg) {
            int msel = (br >> 4) & 3, rsel = br & 3;
#pragma unroll
            for (int n = 0; n < 4; ++n) {
                float vsel = 0.f;
#pragma unroll
                for (int m = 0; m < 4; ++m)
#pragma unroll
                    for (int r = 0; r < 4; ++r)
                        if (m == msel && r == rsel) vsel = acc[m][n][r];
                hsel[l_hop * D + wn * 64 + n * 16 + lr] = vsel;
            }
        }
    }

    float cmax[4];
#pragma unroll
    for (int n = 0; n < 4; ++n) {
        float m0 = acc[0][n][0];
#pragma unroll
        for (int m = 0; m < 4; ++m)
#pragma unroll
            for (int r = 0; r < 4; ++r) m0 = fmaxf(m0, acc[m][n][r]);
        m0 = fmaxf(m0, __shfl_xor(m0, 16, 64));
        m0 = fmaxf(m0, __shfl_xor(m0, 32, 64));
        cmax[n] = m0;
    }
    float* wmaxp = (float*)As;
    if (kg == 0) {
#pragma unroll
        for (int n = 0; n < 4; ++n)
            wmaxp[wm * 128 + wn * 64 + n * 16 + lr] = cmax[n];
    }
    __syncthreads();
    if (tid < 128) {
        float mval = fmaxf(wmaxp[tid], wmaxp[128 + tid]);
        atomicMax(&hmaxk[l_hop * D + tid], encf(mval));
    }
}

// ---- fused gi+GRU+hSt (r16-proven chain math; standalone kernel) ----
__global__ __launch_bounds__(256, 1)
void k_gruF(const float* __restrict__ Wih, const float* __restrict__ bih,
            const float* __restrict__ Whh, const float* __restrict__ bhh,
            const float* __restrict__ pn, const float* __restrict__ query,
            const float* __restrict__ Wfs, const float* __restrict__ bfs,
            const unsigned* __restrict__ hmaxk, const float* __restrict__ hsel,
            float* __restrict__ hbuf, float* __restrict__ hs_ws,
            unsigned* __restrict__ cnts) {
    __shared__ float xs[3 * D];
    const int tid = threadIdx.x;
    const int lane = tid & 63, w = tid >> 6;
    const int bid = blockIdx.x;
    const int j = bid * 4 + w;              // 0..403
    unsigned* cntG = cnts + 1;

    // cache W_ih gate rows (r,z,n) and W_hh rows for j
    float wir[6], wiz[6], win[6];
#pragma unroll
    for (int c = 0; c < 6; ++c) {
        int k = lane + c * 64;
        wir[c] = Wih[(long)j * 384 + k];
        wiz[c] = Wih[(long)(H + j) * 384 + k];
        win[c] = Wih[(long)(2 * H + j) * 384 + k];
    }
    float whr[7], whz[7], whn[7];
#pragma unroll
    for (int c = 0; c < 7; ++c) {
        int i = lane + c * 64;
        bool ok = i < H;
        whr[c] = ok ? Whh[(long)j * H + i]           : 0.f;
        whz[c] = ok ? Whh[(long)(H + j) * H + i]     : 0.f;
        whn[c] = ok ? Whh[(long)(2 * H + j) * H + i] : 0.f;
    }
    const float b_ir = bih[j], b_iz = bih[H + j], b_in = bih[2 * H + j];
    const float b_hr = bhh[j], b_hz = bhh[H + j], b_hn = bhh[2 * H + j];

    for (int t = 0; t < L; ++t) {
        // stage x_t = [hmax[t-1], hsel[t-1], pn[t]] (t=0: [0,0,pn[0]])
        for (int i = tid; i < 384; i += 256) {
            float x;
            if (t == 0)       x = (i < 256) ? 0.f : pn[i - 256];
            else if (i < 128) x = decf(hmaxk[(t - 1) * D + i]);
            else if (i < 256) x = hsel[(t - 1) * D + (i - 128)];
            else              x = pn[t * D + (i - 256)];
            xs[i] = x;
        }
        __syncthreads();
        float gir = 0.f, giz = 0.f, gin = 0.f;
#pragma unroll
        for (int c = 0; c < 6; ++c) {
            float xv = xs[lane + c * 64];
            gir = fmaf(wir[c], xv, gir);
            giz = fmaf(wiz[c], xv, giz);
            gin = fmaf(win[c], xv, gin);
        }
        const float* hin = (t == 0) ? query : (hbuf + ((t - 1) & 1) * H);
        float pr = 0.f, pz = 0.f, pn2 = 0.f;
#pragma unroll
        for (int c = 0; c < 7; ++c) {
            int i = lane + c * 64;
            float hv = 0.f;
            if (i < H) hv = (t == 0) ? hin[i] : aload(hin + i);
            pr  = fmaf(whr[c], hv, pr);
            pz  = fmaf(whz[c], hv, pz);
            pn2 = fmaf(whn[c], hv, pn2);
        }
        for (int off = 1; off < 64; off <<= 1) {
            gir += __shfl_xor(gir, off, 64);
            giz += __shfl_xor(giz, off, 64);
            gin += __shfl_xor(gin, off, 64);
            pr  += __shfl_xor(pr, off, 64);
            pz  += __shfl_xor(pz, off, 64);
            pn2 += __shfl_xor(pn2, off, 64);
        }
        if (lane == 0) {
            float* hout = hbuf + (t & 1) * H;
            float hprev = (t == 0) ? hin[j] : aload(hin + j);
            float r  = sigmoidf_((gir + b_ir) + pr + b_hr);
            float z  = sigmoidf_((giz + b_iz) + pz + b_hz);
            float nn = tanhf((gin + b_in) + r * (pn2 + b_hn));
            astore(hout + j, (1.0f - z) * nn + z * hprev);
        }
        // counter barrier among 101 blocks (incl. t=7 so hbuf[1] visible)
        __syncthreads();
        if (tid == 0) {
            __hip_atomic_fetch_add(cntG, 1u, __ATOMIC_RELEASE,
                                   __HIP_MEMORY_SCOPE_AGENT);
            unsigned target = (unsigned)GRU_BLOCKS * (t + 1);
            while (__hip_atomic_load(cntG, __ATOMIC_ACQUIRE,
                                     __HIP_MEMORY_SCOPE_AGENT) < target)
                __builtin_amdgcn_s_sleep(2);
        }
        __syncthreads();
    }

    // hSt = W_fs qt + b_fs : blocks 0..31
    if (bid < 32) {
        const float* qt = hbuf + H;        // hbuf[1]
        int d = bid * 4 + w;
        float s = 0.f;
#pragma unroll
        for (int c = 0; c < 7; ++c) {
            int i = lane + c * 64;
            if (i < H) s = fmaf(aload(qt + i), Wfs[(long)d * H + i], s);
        }
        for (int off = 1; off < 64; off <<= 1) s += __shfl_xor(s, off, 64);
        if (lane == 0) astore(&hs_ws[d], s + bfs[d]);
    }
}

// ---- hop 7: einsum + hmax7 + in-register uks + full softmax + out write ----
__global__ __launch_bounds__(256, 3)
void k_big7(const float* __restrict__ nb, const unsigned short* __restrict__ wh2,
            const float* __restrict__ bfa, const float* __restrict__ hs_ws,
            const float* __restrict__ Wfp, const float* __restrict__ bfp,
            unsigned* __restrict__ hmaxk, float* __restrict__ pm,
            float* __restrict__ ps, unsigned* __restrict__ cnts,
            float* __restrict__ out) {
    __shared__ float As[128 * 64];
    __shared__ unsigned short Bs[128 * 64];
    __shared__ float sm2[2], ss2[2], red[4], reds[4], bc[2];

    const int bid = blockIdx.x;
    const int row0 = bid * 128;
    const int tid = threadIdx.x;
    const int lane = tid & 63, w = tid >> 6;
    const int wm = w >> 1, wn = w & 1;
    const int lr = lane & 15, kg = lane >> 4;
    unsigned* cntB = cnts + 2;

    const float* xbase = nb + ((long)7 * N + row0) * F;

    f32x4 acc[4][4];
    float bv[4];
#pragma unroll
    for (int n = 0; n < 4; ++n) bv[n] = bfa[wn * 64 + n * 16 + lr];
#pragma unroll
    for (int m = 0; m < 4; ++m)
#pragma unroll
        for (int n = 0; n < 4; ++n) {
            acc[m][n][0] = bv[n]; acc[m][n][1] = bv[n];
            acc[m][n][2] = bv[n]; acc[m][n][3] = bv[n];
        }

    const int srow = lane >> 4;
    const int scp  = lane & 15;

    for (int kt = 0; kt < KT; ++kt) {
        const int fc = kt * 64;
        __syncthreads();
#pragma unroll
        for (int it = 0; it < 8; ++it) {
            int rbase = it * 16 + w * 4;
            int row = rbase + srow;
            int cg = scp ^ (row & 7);
            int col0 = fc + cg * 4;
            const float* src = xbase + (long)row * F + ((col0 < F) ? col0 : 0);
            gld16(src, (char*)As + rbase * 256);
        }
#pragma unroll
        for (int it = 0; it < 4; ++it) {
            int rb = it * 32 + w * 8;
            const char* src = (const char*)wh2 + (long)kt * 16384 + rb * 128 + lane * 16;
            gld16(src, (char*)Bs + rb * 128);
        }
        __syncthreads();

#pragma unroll
        for (int ks = 0; ks < 2; ++ks) {
            half8 b[4];
#pragma unroll
            for (int n = 0; n < 4; ++n) {
                int col = wn * 64 + n * 16 + lr;
                int ch = (ks * 4 + kg) ^ (col & 7);
                b[n] = *(const half8*)((const char*)Bs + col * 128 + ch * 16);
            }
#pragma unroll
            for (int m = 0; m < 4; ++m) {
                int row = wm * 64 + m * 16 + lr;
                int c0 = ks * 8 + kg * 2;
                const char* base = (const char*)As + row * 256;
                float4 x0 = *(const float4*)(base + (((c0)     ^ (row & 7)) << 4));
                float4 x1 = *(const float4*)(base + (((c0 + 1) ^ (row & 7)) << 4));
                half8 a = pack8(x0, x1);
#pragma unroll
                for (int n = 0; n < 4; ++n)
                    acc[m][n] = __builtin_amdgcn_mfma_f32_16x16x32_f16(a, b[n], acc[m][n], 0, 0, 0);
            }
        }
    }

    __syncthreads();

    // uks[row] = sum_col hs[col] * acc (bias folded in acc init)
    float hsv[4];
#pragma unroll
    for (int n = 0; n < 4; ++n) hsv[n] = hs_ws[wn * 64 + n * 16 + lr];
    float p[4][4];
#pragma unroll
    for (int m = 0; m < 4; ++m)
#pragma unroll
        for (int r = 0; r < 4; ++r) {
            float s = hsv[0] * acc[m][0][r];
            s = fmaf(hsv[1], acc[m][1][r], s);
            s = fmaf(hsv[2], acc[m][2][r], s);
            s = fmaf(hsv[3], acc[m][3][r], s);
#pragma unroll
            for (int off = 1; off < 16; off <<= 1)
                s += __shfl_xor(s, off, 64);
            p[m][r] = s;
        }
    float* part = (float*)As;
    if (lr == 0) {
#pragma unroll
        for (int m = 0; m < 4; ++m)
#pragma unroll
            for (int r = 0; r < 4; ++r)
                part[wn * 128 + wm * 64 + m * 16 + kg * 4 + r] = p[m][r];
    }
    __syncthreads();
    float val = -3.4e38f, sv = 0.f;
    if (tid < 128) {
        val = part[tid] + part[128 + tid];
        sv = 1.0f;
    }
    {   // block softmax partial over this block's 128 logits
        float mv = val;
        for (int off = 1; off < 64; off <<= 1) {
            float m2 = __shfl_xor(mv, off, 64);
            float s2 = __shfl_xor(sv, off, 64);
            float M = fmaxf(mv, m2);
            sv = sv * __expf(mv - M) + s2 * __expf(m2 - M);
            mv = M;
        }
        if (lane == 0 && w < 2) { sm2[w] = mv; ss2[w] = sv; }
    }
    __syncthreads();
    if (tid == 0) {
        float M = fmaxf(sm2[0], sm2[1]);
        float S = ss2[0] * __expf(sm2[0] - M) + ss2[1] * __expf(sm2[1] - M);
        astore(&pm[bid], M); astore(&ps[bid], S);
    }

    // column max for hop 7 (u0 needs it) — BEFORE the barrier signal
    {
        __syncthreads();   // part/As reuse safe
        float cmax[4];
#pragma unroll
        for (int n = 0; n < 4; ++n) {
            float m0 = acc[0][n][0];
#pragma unroll
            for (int m = 0; m < 4; ++m)
#pragma unroll
                for (int r = 0; r < 4; ++r) m0 = fmaxf(m0, acc[m][n][r]);
            m0 = fmaxf(m0, __shfl_xor(m0, 16, 64));
            m0 = fmaxf(m0, __shfl_xor(m0, 32, 64));
            cmax[n] = m0;
        }
        float* wmaxp = (float*)As;
        if (kg == 0) {
#pragma unroll
            for (int n = 0; n < 4; ++n)
                wmaxp[wm * 128 + wn * 64 + n * 16 + lr] = cmax[n];
        }
        __syncthreads();
        if (tid < 128) {
            float mval = fmaxf(wmaxp[tid], wmaxp[128 + tid]);
            atomicMax(&hmaxk[7 * D + tid], encf(mval));
        }
    }

    // ---- grid barrier (256 co-resident blocks) ----
    __syncthreads();
    if (tid == 0) {
        __hip_atomic_fetch_add(cntB, 1u, __ATOMIC_RELEASE, __HIP_MEMORY_SCOPE_AGENT);
        while (__hip_atomic_load(cntB, __ATOMIC_ACQUIRE, __HIP_MEMORY_SCOPE_AGENT) < 256u)
            __builtin_amdgcn_s_sleep(2);
    }
    __syncthreads();

    // ---- every block redundantly: u0 + reduce 256 partials -> M, S ----
    float u0 = 0.f;
    if (w == 0) {   // wave 0
        float s = hs_ws[lane] * Wfp[lane];
        s = fmaf(hs_ws[lane + 64], Wfp[lane + 64], s);
        s = fmaf(decf(aloadu(hmaxk + 7 * D + lane)),      Wfp[D + lane],      s);
        s = fmaf(decf(aloadu(hmaxk + 7 * D + lane + 64)), Wfp[D + lane + 64], s);
        for (int off = 1; off < 64; off <<= 1) s += __shfl_xor(s, off, 64);
        u0 = s + bfp[0];
    }
    {
        float m = aload(&pm[tid]), s = aload(&ps[tid]);   // tid<256 exactly
        for (int off = 1; off < 64; off <<= 1) {
            float m2 = __shfl_xor(m, off, 64);
            float s2 = __shfl_xor(s, off, 64);
            float M = fmaxf(m, m2);
            s = s * __expf(m - M) + s2 * __expf(m2 - M);
            m = M;
        }
        if (lane == 0) { red[w] = m; reds[w] = s; }
    }
    __syncthreads();
    if (tid == 0) {
        float M = u0, S = 1.0f;   // fold u0
        for (int k = 0; k < 4; ++k) {
            float Mn = fmaxf(M, red[k]);
            S = S * __expf(M - Mn) + reds[k] * __expf(red[k] - Mn);
            M = Mn;
        }
        bc[0] = M; bc[1] = S;
    }
    __syncthreads();
    {
        float M = bc[0], S = bc[1];
        if (tid < 128) out[1 + row0 + tid] = __expf(val - M) / S;
        if (bid == 0 && tid == 128) {
            // recompute u0 on this thread? u0 lives in wave 0; write from tid 0 path:
        }
        if (bid == 0 && tid == 0) out[0] = __expf(u0 - M) / S;
    }
}

extern "C" void kernel_launch(void* const* d_in, const int* in_sizes, int n_in,
                              void* d_out, int out_size, void* d_ws, size_t ws_size,
                              hipStream_t stream) {
    const float* query = (const float*)d_in[0];
    const float* pn    = (const float*)d_in[1];
    const float* nb    = (const float*)d_in[2];
    const int*   aid   = (const int*)d_in[3];
    const float* Wih   = (const float*)d_in[4];
    const float* Whh   = (const float*)d_in[5];
    const float* bih   = (const float*)d_in[6];
    const float* bhh   = (const float*)d_in[7];
    const float* Wfa   = (const float*)d_in[8];
    const float* bfa   = (const float*)d_in[9];
    const float* Wfs   = (const float*)d_in[10];
    const float* bfs   = (const float*)d_in[11];
    const float* Wfp   = (const float*)d_in[12];
    const float* bfp   = (const float*)d_in[13];

    float* ws = (float*)d_ws;
    unsigned short* wh2   = (unsigned short*)(ws + WS_WH2);
    unsigned*       hmaxk = (unsigned*)(ws + WS_HMAXK);
    unsigned*       cnts  = (unsigned*)(ws + WS_CNT);
    float* hsel   = ws + WS_HSEL;
    float* hbuf   = ws + WS_HBUF;
    float* hs_ws  = ws + WS_HS;
    float* pm     = ws + WS_PM;
    float* psum   = ws + WS_PS;
    float* out    = (float*)d_out;

    k_prep<<<(KT * 128 * 8 + 255) / 256, 256, 0, stream>>>(Wfa, wh2, hmaxk, cnts);
    k_big0<<<(L - 1) * 256, 256, 0, stream>>>(nb, wh2, bfa, aid, hmaxk, hsel);
    k_gruF<<<GRU_BLOCKS, 256, 0, stream>>>(Wih, bih, Whh, bhh, pn, query,
                                           Wfs, bfs, hmaxk, hsel, hbuf, hs_ws, cnts);
    k_big7<<<256, 256, 0, stream>>>(nb, wh2, bfa, hs_ws, Wfp, bfp,
                                    hmaxk, pm, psum, cnts, out);
}